// Round 1
// baseline (390.452 us; speedup 1.0000x reference)
//
#include <hip/hip_runtime.h>
#include <math.h>

#define IMG_W 512
#define IMG_H 512
#define NPLANES 48      // 16 * 3
#define RROWS 88        // output rows per block (multiple of 11)
#define NCHUNK 6        // ceil(512/88)
#define NSTRIP 8        // 512 / 64 cols
#define SSIM_C1 1e-4f
#define SSIM_C2 9e-4f

struct GW { float g[11]; };

__device__ __forceinline__ float fdiv_fast(float n, float d) {
  float r = __builtin_amdgcn_rcpf(d);
  r = r * fmaf(-d, r, 2.0f);      // 1 Newton step on reciprocal
  float q = n * r;
  q = fmaf(fmaf(-d, q, n), r, q); // residual correction
  return q;
}

__global__ __launch_bounds__(64) void ssim_main(
    const float* __restrict__ A, const float* __restrict__ B,
    const float* __restrict__ F, double* __restrict__ accum, GW gw)
{
  __shared__ float sA[80], sB[80], sF[80];
  const int b = blockIdx.x;
  const int plane = b / (NSTRIP * NCHUNK);
  const int rem   = b % (NSTRIP * NCHUNK);
  const int strip = rem / NCHUNK;
  const int chunk = rem % NCHUNK;
  const int x0 = strip * 64;
  const int y0 = chunk * RROWS;
  const int yend = min(y0 + RROWS, IMG_H);
  const int t = threadIdx.x;
  const size_t pbase = (size_t)plane * (IMG_W * IMG_H);
  const float* Ap = A + pbase;
  const float* Bp = B + pbase;
  const float* Fp = F + pbase;

  // ring[stream][slot]: horizontally-convolved rows, slot = input-row-index mod 11
  float ring[8][11];
  #pragma unroll
  for (int s = 0; s < 8; ++s)
    #pragma unroll
    for (int k = 0; k < 11; ++k) ring[s][k] = 0.f;

  float acc = 0.f;
  const int iiMax = yend - y0 + 9;           // last needed input index
  const int c  = x0 - 5 + t;                 // this thread's primary load column
  const bool cok = (c >= 0) && (c < IMG_W);
  const int c2 = c + 64;                     // halo load column (threads 0..9)
  const bool c2ok = (t < 10) && (c2 < IMG_W);

  for (int jj = 0; jj < 9; ++jj) {
    #pragma unroll
    for (int ph = 0; ph < 11; ++ph) {
      const int ii = jj * 11 + ph;           // input-row counter; ii % 11 == ph
      if (ii <= iiMax) {
        const int yin = y0 - 5 + ii;
        const bool rok = (yin >= 0) && (yin < IMG_H);
        const size_t roff = (size_t)yin * IMG_W;
        // --- stage raw row (with zero-padding) into LDS ---
        float vA = 0.f, vB = 0.f, vF = 0.f;
        if (rok && cok) { vA = Ap[roff + c]; vB = Bp[roff + c]; vF = Fp[roff + c]; }
        sA[t] = vA; sB[t] = vB; sF[t] = vF;
        if (t < 10) {
          float wA = 0.f, wB = 0.f, wF = 0.f;
          if (rok && c2ok) { wA = Ap[roff + c2]; wB = Bp[roff + c2]; wF = Fp[roff + c2]; }
          sA[t + 64] = wA; sB[t + 64] = wB; sF[t + 64] = wF;
        }
        __syncthreads();
        // --- horizontal 11-tap conv of the 8 product streams ---
        float hA=0,hB=0,hF=0,hA2=0,hB2=0,hF2=0,hAF=0,hBF=0;
        #pragma unroll
        for (int k = 0; k < 11; ++k) {
          const float w = gw.g[k];
          const float a = sA[t+k], bb = sB[t+k], f = sF[t+k];
          const float wa = w*a, wb = w*bb, wf = w*f;
          hA += wa; hB += wb; hF += wf;
          hA2 = fmaf(wa, a, hA2); hB2 = fmaf(wb, bb, hB2); hF2 = fmaf(wf, f, hF2);
          hAF = fmaf(wa, f, hAF); hBF = fmaf(wb, f, hBF);
        }
        __syncthreads();   // LDS reads done before next phase overwrites
        ring[0][ph]=hA;  ring[1][ph]=hB;  ring[2][ph]=hF;  ring[3][ph]=hA2;
        ring[4][ph]=hB2; ring[5][ph]=hF2; ring[6][ph]=hAF; ring[7][ph]=hBF;

        // --- vertical 11-tap conv + SSIM map once 11 rows are live ---
        if (ii >= 10) {
          const int yout = yin - 5;          // = y0 + ii - 10
          if (yout < yend) {
            float mA=0,mB=0,mF=0,vA2=0,vB2=0,vF2=0,vAF=0,vBF=0;
            #pragma unroll
            for (int k = 0; k < 11; ++k) {
              const int sl = (ph + 1 + k) % 11;   // compile-time constant
              const float w = gw.g[k];
              mA  = fmaf(w, ring[0][sl], mA);
              mB  = fmaf(w, ring[1][sl], mB);
              mF  = fmaf(w, ring[2][sl], mF);
              vA2 = fmaf(w, ring[3][sl], vA2);
              vB2 = fmaf(w, ring[4][sl], vB2);
              vF2 = fmaf(w, ring[5][sl], vF2);
              vAF = fmaf(w, ring[6][sl], vAF);
              vBF = fmaf(w, ring[7][sl], vBF);
            }
            // pair (A,F)
            const float mA2 = mA*mA, mF2 = mF*mF, mAF = mA*mF;
            const float sgA = vA2 - mA2, sgF = vF2 - mF2, sgAF = vAF - mAF;
            const float n1 = fmaf(2.f, mAF, SSIM_C1) * fmaf(2.f, sgAF, SSIM_C2);
            const float d1 = (mA2 + mF2 + SSIM_C1) * (sgA + sgF + SSIM_C2);
            const float s1 = fdiv_fast(n1, d1);
            // pair (B,F)
            const float mB2 = mB*mB, mBF = mB*mF;
            const float sgB = vB2 - mB2, sgBF = vBF - mBF;
            const float n2 = fmaf(2.f, mBF, SSIM_C1) * fmaf(2.f, sgBF, SSIM_C2);
            const float d2 = (mB2 + mF2 + SSIM_C1) * (sgB + sgF + SSIM_C2);
            const float s2 = fdiv_fast(n2, d2);
            acc += s1 + s2;
          }
        }
      }
    }
  }

  // wave (64-lane) reduction, then one fp64 atomic per block
  float wsum = acc;
  #pragma unroll
  for (int off = 32; off > 0; off >>= 1)
    wsum += __shfl_down(wsum, off, 64);
  if (t == 0) atomicAdd(accum, (double)wsum);
}

__global__ void ssim_init(double* accum) { *accum = 0.0; }

__global__ void ssim_final(const double* __restrict__ accum, float* __restrict__ out) {
  // loss = mean(0.5*(map1+map2)) ; we accumulated sum(map1+map2)
  out[0] = (float)(0.5 * (*accum) / (double)(16.0 * 3.0 * 512.0 * 512.0));
}

extern "C" void kernel_launch(void* const* d_in, const int* in_sizes, int n_in,
                              void* d_out, int out_size, void* d_ws, size_t ws_size,
                              hipStream_t stream) {
  const float* A = (const float*)d_in[0];
  const float* B = (const float*)d_in[1];
  const float* F = (const float*)d_in[2];
  double* accum = (double*)d_ws;

  // 1D Gaussian weights in fp64, normalized, cast to fp32 (matches reference numerics)
  GW gw;
  double g[11], s = 0.0;
  for (int i = 0; i < 11; ++i) { g[i] = exp(-((double)((i-5)*(i-5))) / 4.5); s += g[i]; }
  for (int i = 0; i < 11; ++i) gw.g[i] = (float)(g[i] / s);

  hipLaunchKernelGGL(ssim_init, dim3(1), dim3(1), 0, stream, accum);
  hipLaunchKernelGGL(ssim_main, dim3(NPLANES * NSTRIP * NCHUNK), dim3(64), 0, stream,
                     A, B, F, accum, gw);
  hipLaunchKernelGGL(ssim_final, dim3(1), dim3(1), 0, stream, accum, (float*)d_out);
}

// Round 2
// 249.538 us; speedup vs baseline: 1.5647x; 1.5647x over previous
//
#include <hip/hip_runtime.h>
#include <math.h>

#define IMG_W 512
#define IMG_H 512
#define NPLANES 48      // 16 * 3
#define RROWS 32        // output rows per block (512 = 32*16 exact)
#define NCHUNK 16
#define NSTRIP 8        // 512 / 64 cols
#define NBLOCKS (NPLANES * NSTRIP * NCHUNK)   // 6144
#define SSIM_C1 1e-4f
#define SSIM_C2 9e-4f

struct GW { float g[11]; };

__device__ __forceinline__ float fdiv_fast(float n, float d) {
  float r = __builtin_amdgcn_rcpf(d);
  r = r * fmaf(-d, r, 2.0f);      // 1 Newton step on reciprocal
  float q = n * r;
  q = fmaf(fmaf(-d, q, n), r, q); // residual correction
  return q;
}

// One wave per block; 64 output columns x 32 output rows per block.
// No __syncthreads anywhere: single-wave block + double-buffered LDS row;
// in-wave LDS write->read ordering is enforced by compiler lgkmcnt waits.
__global__ __launch_bounds__(64) void ssim_main(
    const float* __restrict__ A, const float* __restrict__ B,
    const float* __restrict__ F, double* __restrict__ partials, GW gw)
{
  __shared__ float sA[2][80], sB[2][80], sF[2][80];
  const int b = blockIdx.x;
  const int plane = b / (NSTRIP * NCHUNK);
  const int rem   = b % (NSTRIP * NCHUNK);
  const int strip = rem / NCHUNK;
  const int chunk = rem % NCHUNK;
  const int x0 = strip * 64;
  const int y0 = chunk * RROWS;
  const int t = threadIdx.x;
  const size_t pbase = (size_t)plane * (IMG_W * IMG_H);
  const float* Ap = A + pbase;
  const float* Bp = B + pbase;
  const float* Fp = F + pbase;

  const int c  = x0 - 5 + t;                 // primary load column
  const bool cok = (c >= 0) && (c < IMG_W);
  const int c2 = c + 64;                     // halo column (threads 0..9)
  const bool c2ok = (t < 10) && (c2 < IMG_W);

  // ring[stream][slot]: horizontally-convolved rows, slot = input-row mod 11
  float ring[8][11];
  #pragma unroll
  for (int s = 0; s < 8; ++s)
    #pragma unroll
    for (int k = 0; k < 11; ++k) ring[s][k] = 0.f;

  float acc = 0.f;

  // prefetch registers for the software pipeline
  float rA, rB, rF, xA, xB, xF;
  auto load_row = [&](int ii) {
    const int yin = y0 - 5 + ii;
    const bool rok = (yin >= 0) && (yin < IMG_H);
    const size_t roff = (size_t)yin * IMG_W;
    rA = (rok && cok) ? Ap[roff + c] : 0.f;
    rB = (rok && cok) ? Bp[roff + c] : 0.f;
    rF = (rok && cok) ? Fp[roff + c] : 0.f;
    xA = (rok && c2ok) ? Ap[roff + c2] : 0.f;
    xB = (rok && c2ok) ? Bp[roff + c2] : 0.f;
    xF = (rok && c2ok) ? Fp[roff + c2] : 0.f;
  };

  load_row(0);   // preload row 0

  for (int jj = 0; jj < 4; ++jj) {
    #pragma unroll
    for (int ph = 0; ph < 11; ++ph) {
      const int ii = jj * 11 + ph;           // input-row counter; ii % 11 == ph
      if (ii <= RROWS + 9) {                 // 0..41
        const int buf = ii & 1;
        // --- stage prefetched row into LDS (double-buffered, no barrier) ---
        sA[buf][t] = rA; sB[buf][t] = rB; sF[buf][t] = rF;
        if (t < 10) { sA[buf][t+64] = xA; sB[buf][t+64] = xB; sF[buf][t+64] = xF; }
        // --- issue NEXT row's global loads; latency hidden under the convs ---
        if (ii < RROWS + 9) load_row(ii + 1);
        // --- horizontal 11-tap conv of the 8 product streams ---
        float hA=0,hB=0,hF=0,hA2=0,hB2=0,hF2=0,hAF=0,hBF=0;
        #pragma unroll
        for (int k = 0; k < 11; ++k) {
          const float w = gw.g[k];
          const float a = sA[buf][t+k], bb = sB[buf][t+k], f = sF[buf][t+k];
          const float wa = w*a, wb = w*bb, wf = w*f;
          hA += wa; hB += wb; hF += wf;
          hA2 = fmaf(wa, a, hA2); hB2 = fmaf(wb, bb, hB2); hF2 = fmaf(wf, f, hF2);
          hAF = fmaf(wa, f, hAF); hBF = fmaf(wb, f, hBF);
        }
        ring[0][ph]=hA;  ring[1][ph]=hB;  ring[2][ph]=hF;  ring[3][ph]=hA2;
        ring[4][ph]=hB2; ring[5][ph]=hF2; ring[6][ph]=hAF; ring[7][ph]=hBF;

        // --- vertical 11-tap conv + SSIM map once 11 rows are live ---
        if (ii >= 10) {                      // yout = y0+ii-10, always in range
          float mA=0,mB=0,mF=0,vA2=0,vB2=0,vF2=0,vAF=0,vBF=0;
          #pragma unroll
          for (int k = 0; k < 11; ++k) {
            const int sl = (ph + 1 + k) % 11;   // compile-time constant
            const float w = gw.g[k];
            mA  = fmaf(w, ring[0][sl], mA);
            mB  = fmaf(w, ring[1][sl], mB);
            mF  = fmaf(w, ring[2][sl], mF);
            vA2 = fmaf(w, ring[3][sl], vA2);
            vB2 = fmaf(w, ring[4][sl], vB2);
            vF2 = fmaf(w, ring[5][sl], vF2);
            vAF = fmaf(w, ring[6][sl], vAF);
            vBF = fmaf(w, ring[7][sl], vBF);
          }
          const float mA2 = mA*mA, mF2 = mF*mF, mAF = mA*mF;
          const float sgA = vA2 - mA2, sgF = vF2 - mF2, sgAF = vAF - mAF;
          const float n1 = fmaf(2.f, mAF, SSIM_C1) * fmaf(2.f, sgAF, SSIM_C2);
          const float d1 = (mA2 + mF2 + SSIM_C1) * (sgA + sgF + SSIM_C2);
          const float s1 = fdiv_fast(n1, d1);
          const float mB2 = mB*mB, mBF = mB*mF;
          const float sgB = vB2 - mB2, sgBF = vBF - mBF;
          const float n2 = fmaf(2.f, mBF, SSIM_C1) * fmaf(2.f, sgBF, SSIM_C2);
          const float d2 = (mB2 + mF2 + SSIM_C1) * (sgB + sgF + SSIM_C2);
          const float s2 = fdiv_fast(n2, d2);
          acc += s1 + s2;
        }
      }
    }
  }

  // wave (64-lane) reduction, one plain store per block (no atomics, no init)
  float wsum = acc;
  #pragma unroll
  for (int off = 32; off > 0; off >>= 1)
    wsum += __shfl_down(wsum, off, 64);
  if (t == 0) partials[b] = (double)wsum;
}

__global__ __launch_bounds__(256) void ssim_final(
    const double* __restrict__ partials, float* __restrict__ out)
{
  __shared__ double sd[256];
  const int t = threadIdx.x;
  double s = 0.0;
  for (int i = t; i < NBLOCKS; i += 256) s += partials[i];
  sd[t] = s;
  __syncthreads();
  for (int off = 128; off > 0; off >>= 1) {
    if (t < off) sd[t] += sd[t + off];
    __syncthreads();
  }
  if (t == 0)
    out[0] = (float)(0.5 * sd[0] / (double)(16.0 * 3.0 * 512.0 * 512.0));
}

extern "C" void kernel_launch(void* const* d_in, const int* in_sizes, int n_in,
                              void* d_out, int out_size, void* d_ws, size_t ws_size,
                              hipStream_t stream) {
  const float* A = (const float*)d_in[0];
  const float* B = (const float*)d_in[1];
  const float* F = (const float*)d_in[2];
  double* partials = (double*)d_ws;   // NBLOCKS doubles = 48 KB

  GW gw;
  double g[11], s = 0.0;
  for (int i = 0; i < 11; ++i) { g[i] = exp(-((double)((i-5)*(i-5))) / 4.5); s += g[i]; }
  for (int i = 0; i < 11; ++i) gw.g[i] = (float)(g[i] / s);

  hipLaunchKernelGGL(ssim_main, dim3(NBLOCKS), dim3(64), 0, stream,
                     A, B, F, partials, gw);
  hipLaunchKernelGGL(ssim_final, dim3(1), dim3(256), 0, stream,
                     partials, (float*)d_out);
}